// Round 7
// baseline (231.807 us; speedup 1.0000x reference)
//
#include <hip/hip_runtime.h>
#include <hip/hip_fp16.h>

#define H_  64      // B*N heads
#define D_  128
#define L_  2048
#define PRE 0.35709578f   // sqrt(log2(e)/sqrt(128)); exp(S/sqrt(D)) = 2^(S')
#define SLOTS 17          // 0..14: off-diag col partials | 15: row-acc | 16: diag

typedef _Float16 half8 __attribute__((ext_vector_type(8)));
typedef float    f32x4 __attribute__((ext_vector_type(4)));

__device__ __forceinline__ float fast_exp2(float x) { return __builtin_exp2f(x); }

__device__ __forceinline__ void gload16(const void* g, void* l) {
    __builtin_amdgcn_global_load_lds(
        (const __attribute__((address_space(1))) void*)g,
        (__attribute__((address_space(3))) void*)l,
        16, 0, 0);
}

// Stage 32KB (128 rows x 256B) with 8 waves: 4 instrs/wave.
// Linear LDS dest, pre-swizzled global src (byte ^= (row&7)<<4 per 256B row).
__device__ __forceinline__ void stage32k8(const char* __restrict__ src,
                                          char* __restrict__ dst,
                                          int wid, int lane) {
#pragma unroll
    for (int jj = 0; jj < 4; ++jj) {
        const unsigned o   = (unsigned)(wid * 4 + jj) * 1024u + (unsigned)lane * 16u;
        const unsigned row = o >> 8;
        const unsigned so  = (o & ~255u) | ((o & 255u) ^ ((row & 7u) << 4));
        gload16(src + so, dst + (size_t)(wid * 4 + jj) * 1024u);
    }
}

// ---------------------------------------------------------------------------
// Kernel 1: x [H][D][L] fp32 -> xt [H][L][D] fp16, scaled by PRE
// ---------------------------------------------------------------------------
__global__ __launch_bounds__(256) void k_transpose(const float* __restrict__ x,
                                                   __half* __restrict__ xt) {
    const int h  = blockIdx.x;
    const int lc = blockIdx.y;
    __shared__ float raw[128][65];
    const float* xh = x + (size_t)h * D_ * L_ + (size_t)lc * 64;
    const int t = threadIdx.x;
    const int r0 = t >> 4;
    const int c4 = (t & 15) << 2;
#pragma unroll
    for (int i = 0; i < 8; ++i) {
        const int d = i * 16 + r0;
        const float4 v = *(const float4*)(xh + (size_t)d * L_ + c4);
        raw[d][c4 + 0] = v.x; raw[d][c4 + 1] = v.y;
        raw[d][c4 + 2] = v.z; raw[d][c4 + 3] = v.w;
    }
    __syncthreads();
    const int lane = t & 63, w = t >> 6;
    __half2* xth = (__half2*)(xt + (size_t)h * L_ * D_ + (size_t)lc * 64 * D_);
#pragma unroll
    for (int i = 0; i < 16; ++i) {
        const int jl = w * 16 + i;
        const float a = raw[2 * lane][jl] * PRE;
        const float b = raw[2 * lane + 1][jl] * PRE;
        xth[(size_t)jl * 64 + lane] = __floats2half2_rn(a, b);
    }
}

// ---------------------------------------------------------------------------
// Kernel 2: symmetric panel-persistent Gram GEMM.
//   512 thr = 8 waves (4 row-groups x 2 col-groups; wave tile 32x64).
//   A-frags in registers (read once/panel); B double-buffered (tile it ->
//   buf[it&1], diag/A alias buf0). ONE __syncthreads per step (compiler-
//   managed waits — no asm sync). Column sums go through a parity-double-
//   buffered csum LDS buffer, flushed to global during the NEXT step.
//   LDS 78KB -> 2 blocks/CU = 16 waves/CU (4/SIMD).
// ---------------------------------------------------------------------------
template <int PASS>
__global__ __launch_bounds__(512, 4) void k_gemm(const __half* __restrict__ xt,
                                                 const float* __restrict__ ainv,
                                                 float* __restrict__ zw) {
    __shared__ char  sm[65536];        // buf0 [0,32K): A/diag + even B; buf1: odd B
    __shared__ float aS[2048];
    __shared__ float csum[2][4][128];
    __shared__ float zfin[2][128];

    const int bid = blockIdx.x;
    const int res = bid & 7;           // XCD pinning
    const int j   = bid >> 3;
    const int h   = ((j >> 3) << 3) | res;
    const int pid = j & 7;

    const int t    = threadIdx.x;
    const int lane = t & 63;
    const int wid  = t >> 6;           // 0..7
    const int wr   = wid >> 1;         // 0..3: 32-row group
    const int wc   = wid & 1;          // 0..1: 64-col group
    const int lo   = lane & 15, hi = lane >> 4;
    const unsigned sx   = (unsigned)((lane & 7) << 4);
    const unsigned rowA = (unsigned)(wr * 32 + lo);
    const unsigned rowB = (unsigned)(wc * 64 + lo);

    const char* xh  = (const char*)(xt + (size_t)h * (L_ * D_));
    float*      zwh = zw + (size_t)h * SLOTS * 2048;

    if (PASS == 2)                     // ainv -> LDS once (512 thr x 4 floats)
        *(float4*)&aS[t * 4] = ((const float4*)(ainv + ((size_t)h << 11)))[t];

#pragma unroll 1
    for (int pp = 0; pp < 2; ++pp) {
        const int p  = pp ? (15 - pid) : pid;
        const int NS = 15 - p;         // off-diag steps

        stage32k8(xh + (size_t)p * 32768, sm, wid, lane);
        if (NS > 0) stage32k8(xh + (size_t)(p + 1) * 32768, sm + 32768, wid, lane);
        __syncthreads();               // A + B1 landed; prev panel LDS consumed

        // ---- A fragments -> registers (live whole panel)
        half8 afr[2][4];
#pragma unroll
        for (int fm = 0; fm < 2; ++fm)
#pragma unroll
            for (int s = 0; s < 4; ++s)
                afr[fm][s] = *(const half8*)(sm + (rowA + fm * 16) * 256
                                                + (((unsigned)(s * 64 + hi * 16)) ^ sx));
        float rs[2][4] = {};           // pass1: row sums; pass2: sym row-weighted
        float ar[2][4];
        if (PASS == 2) {
#pragma unroll
            for (int fm = 0; fm < 2; ++fm)
#pragma unroll
                for (int r = 0; r < 4; ++r)
                    ar[fm][r] = aS[p * 128 + wr * 32 + fm * 16 + hi * 4 + r];
        }

#pragma unroll 1
        for (int it = 0; it <= NS; ++it) {
            const int ct = p + it;
            if (it > 0) __syncthreads();            // B(it) drained+visible; csum(it-1) visible
            if (it < NS)
                stage32k8(xh + (size_t)(ct + 1) * 32768,
                          sm + (((it + 1) & 1) ? 32768 : 0), wid, lane);
            if (it >= 1 && t < 128) {               // flush prev column's partials
                const int pr = (it - 1) & 1;
                const float v = csum[pr][0][t] + csum[pr][1][t]
                              + csum[pr][2][t] + csum[pr][3][t];
                if (it == 1) { if (PASS == 2) zwh[((size_t)16 << 11) + (size_t)p * 128 + t] = v; }
                else         zwh[((size_t)p << 11) + (size_t)(ct - 1) * 128 + t] = v;
            }

            const char* bbuf = (it == 0) ? sm : (sm + ((it & 1) ? 32768 : 0));
            float acol[4];
            if (PASS == 2) {
#pragma unroll
                for (int fn = 0; fn < 4; ++fn)
                    acol[fn] = aS[ct * 128 + wc * 64 + fn * 16 + lo];
            }

            f32x4 acc[2][4] = {};
            __builtin_amdgcn_s_setprio(1);
#pragma unroll
            for (int s = 0; s < 4; ++s) {
                const unsigned inr = ((unsigned)(s * 64 + hi * 16)) ^ sx;
                half8 b[4];
#pragma unroll
                for (int fn = 0; fn < 4; ++fn)
                    b[fn] = *(const half8*)(bbuf + (rowB + fn * 16) * 256 + inr);
#pragma unroll
                for (int fm = 0; fm < 2; ++fm)
#pragma unroll
                    for (int fn = 0; fn < 4; ++fn)
                        acc[fm][fn] = __builtin_amdgcn_mfma_f32_16x16x32_f16(
                            afr[fm][s], b[fn], acc[fm][fn], 0, 0, 0);
            }
            __builtin_amdgcn_s_setprio(0);

            float cs[4] = {0.f, 0.f, 0.f, 0.f};
#pragma unroll
            for (int fm = 0; fm < 2; ++fm)
#pragma unroll
                for (int fn = 0; fn < 4; ++fn)
#pragma unroll
                    for (int r = 0; r < 4; ++r) {
                        const float e = fast_exp2(acc[fm][fn][r]);
                        if (PASS == 1) { rs[fm][r] += e; cs[fn] += e; }
                        else           { cs[fn] += ar[fm][r] * e;
                                         if (it > 0) rs[fm][r] += acol[fn] * e; }
                    }
            if (!(PASS == 1 && it == 0)) {          // pass1 diag: rows only
#pragma unroll
                for (int fn = 0; fn < 4; ++fn) {
                    cs[fn] += __shfl_xor(cs[fn], 16, 64);
                    cs[fn] += __shfl_xor(cs[fn], 32, 64);
                }
                if (lane < 16) {
#pragma unroll
                    for (int fn = 0; fn < 4; ++fn)
                        csum[it & 1][wr][wc * 64 + fn * 16 + lane] = cs[fn];
                }
            }
        }

        // ---- panel end: rs over 16 col-lanes; flush zfin + last csum column
#pragma unroll
        for (int fm = 0; fm < 2; ++fm)
#pragma unroll
            for (int r = 0; r < 4; ++r) {
                float v = rs[fm][r];
                v += __shfl_xor(v, 1, 64);
                v += __shfl_xor(v, 2, 64);
                v += __shfl_xor(v, 4, 64);
                v += __shfl_xor(v, 8, 64);
                if (lo == 0) zfin[wc][wr * 32 + fm * 16 + hi * 4 + r] = v;
            }
        __syncthreads();
        if (t < 128) {
            zwh[((size_t)15 << 11) + ((size_t)p << 7) + t] = zfin[0][t] + zfin[1][t];
            const int pr = NS & 1;
            const float v = csum[pr][0][t] + csum[pr][1][t]
                          + csum[pr][2][t] + csum[pr][3][t];
            if (NS == 0) { if (PASS == 2) zwh[((size_t)16 << 11) + (size_t)p * 128 + t] = v; }
            else         zwh[((size_t)p << 11) + (size_t)(p + NS) * 128 + t] = v;
        }
    }
}

// ---------------------------------------------------------------------------
// Kernel 3: Z[l] = slot15 + sum_{p<q} slot_p ; Ainv = 1/Z   (q = l>>7)
// ---------------------------------------------------------------------------
__global__ __launch_bounds__(256) void k_reduceZ(const float* __restrict__ zp,
                                                 float* __restrict__ ainv) {
    const int i = blockIdx.x * 256 + threadIdx.x;   // over H_*L_
    const int h = i >> 11, l = i & 2047, q = l >> 7;
    const float* zh = zp + (size_t)h * SLOTS * 2048;
    float z = zh[((size_t)15 << 11) + l];
#pragma unroll
    for (int p = 0; p < 15; ++p)
        if (p < q) z += zh[((size_t)p << 11) + l];
    ainv[i] = 1.0f / z;
}

// ---------------------------------------------------------------------------
// Kernel 4: w = slot15 + slot16 + sum_{p<q} slot_p ; out = (1/L) x . w
// ---------------------------------------------------------------------------
__global__ __launch_bounds__(256) void k_out(const float* __restrict__ x,
                                             const float* __restrict__ wp,
                                             float* __restrict__ out) {
    __shared__ float wl[L_];
    const int h = blockIdx.x >> 2, qb = blockIdx.x & 3;
    const int t = threadIdx.x, lane = t & 63, wid = t >> 6;
    const float* wh = wp + (size_t)h * SLOTS * 2048;
    for (int c = t; c < L_; c += 256) {
        const int q = c >> 7;
        float s = wh[((size_t)15 << 11) + c] + wh[((size_t)16 << 11) + c];
#pragma unroll
        for (int p = 0; p < 15; ++p)
            if (p < q) s += wh[((size_t)p << 11) + c];
        wl[c] = s;
    }
    __syncthreads();
#pragma unroll 1
    for (int it = 0; it < 8; ++it) {
        const int d = qb * 32 + wid * 8 + it;
        const float* xr = x + ((size_t)h * D_ + d) * L_;
        float s = 0.0f;
#pragma unroll
        for (int kk = 0; kk < 8; ++kk) {
            const int m = kk * 256 + lane * 4;
            const float4 xv = *(const float4*)(xr + m);
            const float4 wv = *(const float4*)(wl + m);
            s += xv.x * wv.x + xv.y * wv.y + xv.z * wv.z + xv.w * wv.w;
        }
#pragma unroll
        for (int dm = 1; dm < 64; dm <<= 1) s += __shfl_xor(s, dm, 64);
        if (lane == 0) out[(size_t)h * D_ + d] = s * (1.0f / (float)L_);
    }
}

// ---------------------------------------------------------------------------
extern "C" void kernel_launch(void* const* d_in, const int* in_sizes, int n_in,
                              void* d_out, int out_size, void* d_ws, size_t ws_size,
                              hipStream_t stream) {
    const float* x = (const float*)d_in[0];
    float* out = (float*)d_out;
    char* ws = (char*)d_ws;

    // workspace: xt 33,554,432 | zwp 17 slots = 8,912,896 | ainv 524,288
    __half* xt  = (__half*)(ws);
    float* zwp  = (float*)(ws + 33554432);
    float* ainv = (float*)(ws + 33554432 + 8912896);

    k_transpose<<<dim3(H_, L_ / 64), 256, 0, stream>>>(x, xt);
    k_gemm<1><<<512, 512, 0, stream>>>(xt, ainv, zwp);
    k_reduceZ<<<(H_ * L_) / 256, 256, 0, stream>>>(zwp, ainv);
    k_gemm<2><<<512, 512, 0, stream>>>(xt, ainv, zwp);
    k_out<<<H_ * 4, 256, 0, stream>>>(x, zwp, out);
}

// Round 8
// 195.095 us; speedup vs baseline: 1.1882x; 1.1882x over previous
//
#include <hip/hip_runtime.h>
#include <hip/hip_fp16.h>

#define H_  64      // B*N heads
#define D_  128
#define L_  2048
#define PRE 0.35709578f   // sqrt(log2(e)/sqrt(128)); exp(S/sqrt(D)) = 2^(S')
#define SLOTS 17          // 0..14: off-diag col partials | 15: row-acc | 16: diag

typedef _Float16 half8 __attribute__((ext_vector_type(8)));
typedef float    f32x4 __attribute__((ext_vector_type(4)));

__device__ __forceinline__ float fast_exp2(float x) { return __builtin_exp2f(x); }

__device__ __forceinline__ void gload16(const void* g, void* l) {
    __builtin_amdgcn_global_load_lds(
        (const __attribute__((address_space(1))) void*)g,
        (__attribute__((address_space(3))) void*)l,
        16, 0, 0);
}

// Stage 32KB (128 rows x 256B) with 4 waves: 8 instrs/wave.
// Linear LDS dest, pre-swizzled global src (byte ^= (row&7)<<4 per 256B row).
__device__ __forceinline__ void stage32k(const char* __restrict__ src,
                                         char* __restrict__ dst,
                                         int wid, int lane) {
#pragma unroll
    for (int jj = 0; jj < 8; ++jj) {
        const unsigned o   = (unsigned)(wid * 8 + jj) * 1024u + (unsigned)lane * 16u;
        const unsigned row = o >> 8;
        const unsigned so  = (o & ~255u) | ((o & 255u) ^ ((row & 7u) << 4));
        gload16(src + so, dst + (size_t)(wid * 8 + jj) * 1024u);
    }
}

// ---------------------------------------------------------------------------
// Kernel 1: x [H][D][L] fp32 -> xt [H][L][D] fp16, scaled by PRE
// ---------------------------------------------------------------------------
__global__ __launch_bounds__(256) void k_transpose(const float* __restrict__ x,
                                                   __half* __restrict__ xt) {
    const int h  = blockIdx.x;
    const int lc = blockIdx.y;
    __shared__ float raw[128][65];
    const float* xh = x + (size_t)h * D_ * L_ + (size_t)lc * 64;
    const int t = threadIdx.x;
    const int r0 = t >> 4;
    const int c4 = (t & 15) << 2;
#pragma unroll
    for (int i = 0; i < 8; ++i) {
        const int d = i * 16 + r0;
        const float4 v = *(const float4*)(xh + (size_t)d * L_ + c4);
        raw[d][c4 + 0] = v.x; raw[d][c4 + 1] = v.y;
        raw[d][c4 + 2] = v.z; raw[d][c4 + 3] = v.w;
    }
    __syncthreads();
    const int lane = t & 63, w = t >> 6;
    __half2* xth = (__half2*)(xt + (size_t)h * L_ * D_ + (size_t)lc * 64 * D_);
#pragma unroll
    for (int i = 0; i < 16; ++i) {
        const int jl = w * 16 + i;
        const float a = raw[2 * lane][jl] * PRE;
        const float b = raw[2 * lane + 1][jl] * PRE;
        xth[(size_t)jl * 64 + lane] = __floats2half2_rn(a, b);
    }
}

// ---------------------------------------------------------------------------
// Kernel 2: symmetric panel-persistent Gram GEMM.
//   256 thr = 4 waves (2x2; wave tile 64x64). A-frags in registers (read
//   once/panel); B double-buffered (tile it -> buf[it&1]; A/diag alias buf0).
//   ONE __syncthreads per step, compiler-managed waits (no asm sync — R4-R6
//   lesson). Column sums parity-buffered in csum, flushed NEXT step.
//   fn-halved acc (acc[4][2] x2) keeps VGPR under the spill line (R5 lesson).
//   LDS ~74KB -> 2 blocks/CU desync (R3 lesson).
// ---------------------------------------------------------------------------
template <int PASS>
__global__ __launch_bounds__(256, 2) void k_gemm(const __half* __restrict__ xt,
                                                 const float* __restrict__ ainv,
                                                 float* __restrict__ zw) {
    __shared__ char  sm[65536];        // buf0 [0,32K): A/diag + even B; buf1: odd B
    __shared__ float aS[2048];
    __shared__ float csum[2][2][128];
    __shared__ float zfin[2][128];

    const int bid = blockIdx.x;
    const int res = bid & 7;           // XCD pinning
    const int j   = bid >> 3;
    const int h   = ((j >> 3) << 3) | res;
    const int pid = j & 7;

    const int t    = threadIdx.x;
    const int lane = t & 63;
    const int wid  = t >> 6;           // 0..3
    const int wr   = wid >> 1;         // 0..1: 64-row group
    const int wc   = wid & 1;          // 0..1: 64-col group
    const int lo   = lane & 15, hi = lane >> 4;
    const unsigned sx   = (unsigned)((lane & 7) << 4);
    const unsigned rowA = (unsigned)(wr * 64 + lo);
    const unsigned rowB = (unsigned)(wc * 64 + lo);

    const char* xh  = (const char*)(xt + (size_t)h * (L_ * D_));
    float*      zwh = zw + (size_t)h * SLOTS * 2048;

    if (PASS == 2) {                   // ainv -> LDS once
        const float4* a4 = (const float4*)(ainv + ((size_t)h << 11));
        *(float4*)&aS[t * 8]     = a4[t * 2];
        *(float4*)&aS[t * 8 + 4] = a4[t * 2 + 1];
    }

#pragma unroll 1
    for (int pp = 0; pp < 2; ++pp) {
        const int p  = pp ? (15 - pid) : pid;
        const int NS = 15 - p;         // off-diag steps

        stage32k(xh + (size_t)p * 32768, sm, wid, lane);
        if (NS > 0) stage32k(xh + (size_t)(p + 1) * 32768, sm + 32768, wid, lane);
        __syncthreads();               // A + B1 landed; prev panel LDS consumed

        // ---- A fragments -> registers (live whole panel)
        half8 afr[4][4];
#pragma unroll
        for (int fm = 0; fm < 4; ++fm)
#pragma unroll
            for (int s = 0; s < 4; ++s)
                afr[fm][s] = *(const half8*)(sm + (rowA + fm * 16) * 256
                                                + (((unsigned)(s * 64 + hi * 16)) ^ sx));
        float rs[4][4] = {};           // pass1: row sums; pass2: sym row-weighted
        float ar[4][4];
        if (PASS == 2) {
#pragma unroll
            for (int fm = 0; fm < 4; ++fm)
#pragma unroll
                for (int r = 0; r < 4; ++r)
                    ar[fm][r] = aS[p * 128 + wr * 64 + fm * 16 + hi * 4 + r];
        }

#pragma unroll 1
        for (int it = 0; it <= NS; ++it) {
            const int ct = p + it;
            if (it > 0) __syncthreads();            // B(it) drained; csum(it-1) visible
            if (it < NS)
                stage32k(xh + (size_t)(ct + 1) * 32768,
                         sm + (((it + 1) & 1) ? 32768 : 0), wid, lane);
            if (it >= 1 && t < 128) {               // flush prev column's partials
                const int pr = (it - 1) & 1;
                const float v = csum[pr][0][t] + csum[pr][1][t];
                if (it == 1) { if (PASS == 2) zwh[((size_t)16 << 11) + (size_t)p * 128 + t] = v; }
                else         zwh[((size_t)p << 11) + (size_t)(ct - 1) * 128 + t] = v;
            }

            const char* bbuf = (it == 0) ? sm : (sm + ((it & 1) ? 32768 : 0));

#pragma unroll 1
            for (int hf = 0; hf < 2; ++hf) {
                float acol[2];
                if (PASS == 2) {
#pragma unroll
                    for (int f = 0; f < 2; ++f)
                        acol[f] = aS[ct * 128 + wc * 64 + (hf * 2 + f) * 16 + lo];
                }
                f32x4 acc[4][2] = {};
                __builtin_amdgcn_s_setprio(1);
#pragma unroll
                for (int s = 0; s < 4; ++s) {
                    const unsigned inr = ((unsigned)(s * 64 + hi * 16)) ^ sx;
                    half8 b[2];
#pragma unroll
                    for (int f = 0; f < 2; ++f)
                        b[f] = *(const half8*)(bbuf + (rowB + (unsigned)(hf * 2 + f) * 16) * 256 + inr);
#pragma unroll
                    for (int fm = 0; fm < 4; ++fm)
#pragma unroll
                        for (int fn = 0; fn < 2; ++fn)
                            acc[fm][fn] = __builtin_amdgcn_mfma_f32_16x16x32_f16(
                                afr[fm][s], b[fn], acc[fm][fn], 0, 0, 0);
                }
                __builtin_amdgcn_s_setprio(0);

                float cs[2] = {0.f, 0.f};
#pragma unroll
                for (int fm = 0; fm < 4; ++fm)
#pragma unroll
                    for (int fn = 0; fn < 2; ++fn)
#pragma unroll
                        for (int r = 0; r < 4; ++r) {
                            const float e = fast_exp2(acc[fm][fn][r]);
                            if (PASS == 1) { rs[fm][r] += e; cs[fn] += e; }
                            else           { cs[fn] += ar[fm][r] * e;
                                             if (it > 0) rs[fm][r] += acol[fn] * e; }
                        }
                if (!(PASS == 1 && it == 0)) {      // pass1 diag: rows only
#pragma unroll
                    for (int fn = 0; fn < 2; ++fn) {
                        cs[fn] += __shfl_xor(cs[fn], 16, 64);
                        cs[fn] += __shfl_xor(cs[fn], 32, 64);
                    }
                    if (lane < 16) {
#pragma unroll
                        for (int fn = 0; fn < 2; ++fn)
                            csum[it & 1][wr][wc * 64 + (hf * 2 + fn) * 16 + lane] = cs[fn];
                    }
                }
            }
        }

        // ---- panel end: rs over 16 col-lanes; flush zfin + last csum column
#pragma unroll
        for (int fm = 0; fm < 4; ++fm)
#pragma unroll
            for (int r = 0; r < 4; ++r) {
                float v = rs[fm][r];
                v += __shfl_xor(v, 1, 64);
                v += __shfl_xor(v, 2, 64);
                v += __shfl_xor(v, 4, 64);
                v += __shfl_xor(v, 8, 64);
                if (lo == 0) zfin[wc][wr * 64 + fm * 16 + hi * 4 + r] = v;
            }
        __syncthreads();
        if (t < 128) {
            zwh[((size_t)15 << 11) + ((size_t)p << 7) + t] = zfin[0][t] + zfin[1][t];
            const int pr = NS & 1;
            const float v = csum[pr][0][t] + csum[pr][1][t];
            if (NS == 0) { if (PASS == 2) zwh[((size_t)16 << 11) + (size_t)p * 128 + t] = v; }
            else         zwh[((size_t)p << 11) + (size_t)(p + NS) * 128 + t] = v;
        }
    }
}

// ---------------------------------------------------------------------------
// Kernel 3: Z[l] = slot15 + sum_{p<q} slot_p ; Ainv = 1/Z   (q = l>>7)
// ---------------------------------------------------------------------------
__global__ __launch_bounds__(256) void k_reduceZ(const float* __restrict__ zp,
                                                 float* __restrict__ ainv) {
    const int i = blockIdx.x * 256 + threadIdx.x;   // over H_*L_
    const int h = i >> 11, l = i & 2047, q = l >> 7;
    const float* zh = zp + (size_t)h * SLOTS * 2048;
    float z = zh[((size_t)15 << 11) + l];
#pragma unroll
    for (int p = 0; p < 15; ++p)
        if (p < q) z += zh[((size_t)p << 11) + l];
    ainv[i] = 1.0f / z;
}

// ---------------------------------------------------------------------------
// Kernel 4: w = slot15 + slot16 + sum_{p<q} slot_p ; out = (1/L) x . w
// ---------------------------------------------------------------------------
__global__ __launch_bounds__(256) void k_out(const float* __restrict__ x,
                                             const float* __restrict__ wp,
                                             float* __restrict__ out) {
    __shared__ float wl[L_];
    const int h = blockIdx.x >> 2, qb = blockIdx.x & 3;
    const int t = threadIdx.x, lane = t & 63, wid = t >> 6;
    const float* wh = wp + (size_t)h * SLOTS * 2048;
    for (int c = t; c < L_; c += 256) {
        const int q = c >> 7;
        float s = wh[((size_t)15 << 11) + c] + wh[((size_t)16 << 11) + c];
#pragma unroll
        for (int p = 0; p < 15; ++p)
            if (p < q) s += wh[((size_t)p << 11) + c];
        wl[c] = s;
    }
    __syncthreads();
#pragma unroll 1
    for (int it = 0; it < 8; ++it) {
        const int d = qb * 32 + wid * 8 + it;
        const float* xr = x + ((size_t)h * D_ + d) * L_;
        float s = 0.0f;
#pragma unroll
        for (int kk = 0; kk < 8; ++kk) {
            const int m = kk * 256 + lane * 4;
            const float4 xv = *(const float4*)(xr + m);
            const float4 wv = *(const float4*)(wl + m);
            s += xv.x * wv.x + xv.y * wv.y + xv.z * wv.z + xv.w * wv.w;
        }
#pragma unroll
        for (int dm = 1; dm < 64; dm <<= 1) s += __shfl_xor(s, dm, 64);
        if (lane == 0) out[(size_t)h * D_ + d] = s * (1.0f / (float)L_);
    }
}

// ---------------------------------------------------------------------------
extern "C" void kernel_launch(void* const* d_in, const int* in_sizes, int n_in,
                              void* d_out, int out_size, void* d_ws, size_t ws_size,
                              hipStream_t stream) {
    const float* x = (const float*)d_in[0];
    float* out = (float*)d_out;
    char* ws = (char*)d_ws;

    // workspace: xt 33,554,432 | zwp 17 slots = 8,912,896 | ainv 524,288
    __half* xt  = (__half*)(ws);
    float* zwp  = (float*)(ws + 33554432);
    float* ainv = (float*)(ws + 33554432 + 8912896);

    k_transpose<<<dim3(H_, L_ / 64), 256, 0, stream>>>(x, xt);
    k_gemm<1><<<512, 256, 0, stream>>>(xt, ainv, zwp);
    k_reduceZ<<<(H_ * L_) / 256, 256, 0, stream>>>(zwp, ainv);
    k_gemm<2><<<512, 256, 0, stream>>>(xt, ainv, zwp);
    k_out<<<H_ * 4, 256, 0, stream>>>(x, zwp, out);
}

// Round 9
// 160.410 us; speedup vs baseline: 1.4451x; 1.2162x over previous
//
#include <hip/hip_runtime.h>
#include <hip/hip_fp16.h>

#define H_  64      // B*N heads
#define D_  128
#define L_  2048
#define PRE 0.35709578f   // sqrt(log2(e)/sqrt(128)); exp(S/sqrt(D)) = 2^(S')
#define SLOTS 17          // 0..14: off-diag col partials | 15: row-acc | 16: diag

typedef _Float16 half8 __attribute__((ext_vector_type(8)));
typedef float    f32x4 __attribute__((ext_vector_type(4)));

// RAW v_exp_f32 (no denormal-fixup expansion). R3 vs R4-R8 A/B showed the
// __builtin_exp2f path costs ~2x VALU time kernel-wide (~30us). Flush-to-zero
// on denormal outputs is numerically irrelevant here (sums of e^s >= 1).
__device__ __forceinline__ float fast_exp2(float x) {
#if __has_builtin(__builtin_amdgcn_exp2f)
    return __builtin_amdgcn_exp2f(x);
#else
    return __builtin_exp2f(x);
#endif
}

__device__ __forceinline__ void gload16(const void* g, void* l) {
    __builtin_amdgcn_global_load_lds(
        (const __attribute__((address_space(1))) void*)g,
        (__attribute__((address_space(3))) void*)l,
        16, 0, 0);
}

// Stage 32KB (128 rows x 256B) with 4 waves: 8 instrs/wave.
// Linear LDS dest, pre-swizzled global src (byte ^= (row&7)<<4 per 256B row).
__device__ __forceinline__ void stage32k(const char* __restrict__ src,
                                         char* __restrict__ dst,
                                         int wid, int lane) {
#pragma unroll
    for (int jj = 0; jj < 8; ++jj) {
        const unsigned o   = (unsigned)(wid * 8 + jj) * 1024u + (unsigned)lane * 16u;
        const unsigned row = o >> 8;
        const unsigned so  = (o & ~255u) | ((o & 255u) ^ ((row & 7u) << 4));
        gload16(src + so, dst + (size_t)(wid * 8 + jj) * 1024u);
    }
}

// ---------------------------------------------------------------------------
// Kernel 1: x [H][D][L] fp32 -> xt [H][L][D] fp16, scaled by PRE
// ---------------------------------------------------------------------------
__global__ __launch_bounds__(256) void k_transpose(const float* __restrict__ x,
                                                   __half* __restrict__ xt) {
    const int h  = blockIdx.x;
    const int lc = blockIdx.y;
    __shared__ float raw[128][65];
    const float* xh = x + (size_t)h * D_ * L_ + (size_t)lc * 64;
    const int t = threadIdx.x;
    const int r0 = t >> 4;
    const int c4 = (t & 15) << 2;
#pragma unroll
    for (int i = 0; i < 8; ++i) {
        const int d = i * 16 + r0;
        const float4 v = *(const float4*)(xh + (size_t)d * L_ + c4);
        raw[d][c4 + 0] = v.x; raw[d][c4 + 1] = v.y;
        raw[d][c4 + 2] = v.z; raw[d][c4 + 3] = v.w;
    }
    __syncthreads();
    const int lane = t & 63, w = t >> 6;
    __half2* xth = (__half2*)(xt + (size_t)h * L_ * D_ + (size_t)lc * 64 * D_);
#pragma unroll
    for (int i = 0; i < 16; ++i) {
        const int jl = w * 16 + i;
        const float a = raw[2 * lane][jl] * PRE;
        const float b = raw[2 * lane + 1][jl] * PRE;
        xth[(size_t)jl * 64 + lane] = __floats2half2_rn(a, b);
    }
}

// ---------------------------------------------------------------------------
// Kernel 2: symmetric panel-persistent Gram GEMM.
//   256 thr = 4 waves (2x2; wave tile 64x64). A-frags in registers (read
//   once/panel); B double-buffered (tile it -> buf[it&1]; A/diag alias buf0).
//   ONE __syncthreads per step, compiler-managed waits (no asm sync — R4-R6
//   lesson). Column sums parity-buffered in csum, flushed NEXT step.
//   fn-halved acc (acc[4][2] x2) keeps VGPR under the spill line (R5 lesson).
//   LDS ~74KB -> 2 blocks/CU desync (R3 lesson). Raw v_exp_f32 (R8 lesson).
// ---------------------------------------------------------------------------
template <int PASS>
__global__ __launch_bounds__(256, 2) void k_gemm(const __half* __restrict__ xt,
                                                 const float* __restrict__ ainv,
                                                 float* __restrict__ zw) {
    __shared__ char  sm[65536];        // buf0 [0,32K): A/diag + even B; buf1: odd B
    __shared__ float aS[2048];
    __shared__ float csum[2][2][128];
    __shared__ float zfin[2][128];

    const int bid = blockIdx.x;
    const int res = bid & 7;           // XCD pinning
    const int j   = bid >> 3;
    const int h   = ((j >> 3) << 3) | res;
    const int pid = j & 7;

    const int t    = threadIdx.x;
    const int lane = t & 63;
    const int wid  = t >> 6;           // 0..3
    const int wr   = wid >> 1;         // 0..1: 64-row group
    const int wc   = wid & 1;          // 0..1: 64-col group
    const int lo   = lane & 15, hi = lane >> 4;
    const unsigned sx   = (unsigned)((lane & 7) << 4);
    const unsigned rowA = (unsigned)(wr * 64 + lo);
    const unsigned rowB = (unsigned)(wc * 64 + lo);

    const char* xh  = (const char*)(xt + (size_t)h * (L_ * D_));
    float*      zwh = zw + (size_t)h * SLOTS * 2048;

    if (PASS == 2) {                   // ainv -> LDS once
        const float4* a4 = (const float4*)(ainv + ((size_t)h << 11));
        *(float4*)&aS[t * 8]     = a4[t * 2];
        *(float4*)&aS[t * 8 + 4] = a4[t * 2 + 1];
    }

#pragma unroll 1
    for (int pp = 0; pp < 2; ++pp) {
        const int p  = pp ? (15 - pid) : pid;
        const int NS = 15 - p;         // off-diag steps

        stage32k(xh + (size_t)p * 32768, sm, wid, lane);
        if (NS > 0) stage32k(xh + (size_t)(p + 1) * 32768, sm + 32768, wid, lane);
        __syncthreads();               // A + B1 landed; prev panel LDS consumed

        // ---- A fragments -> registers (live whole panel)
        half8 afr[4][4];
#pragma unroll
        for (int fm = 0; fm < 4; ++fm)
#pragma unroll
            for (int s = 0; s < 4; ++s)
                afr[fm][s] = *(const half8*)(sm + (rowA + fm * 16) * 256
                                                + (((unsigned)(s * 64 + hi * 16)) ^ sx));
        float rs[4][4] = {};           // pass1: row sums; pass2: sym row-weighted
        float ar[4][4];
        if (PASS == 2) {
#pragma unroll
            for (int fm = 0; fm < 4; ++fm)
#pragma unroll
                for (int r = 0; r < 4; ++r)
                    ar[fm][r] = aS[p * 128 + wr * 64 + fm * 16 + hi * 4 + r];
        }

#pragma unroll 1
        for (int it = 0; it <= NS; ++it) {
            const int ct = p + it;
            if (it > 0) __syncthreads();            // B(it) drained; csum(it-1) visible
            if (it < NS)
                stage32k(xh + (size_t)(ct + 1) * 32768,
                         sm + (((it + 1) & 1) ? 32768 : 0), wid, lane);
            if (it >= 1 && t < 128) {               // flush prev column's partials
                const int pr = (it - 1) & 1;
                const float v = csum[pr][0][t] + csum[pr][1][t];
                if (it == 1) { if (PASS == 2) zwh[((size_t)16 << 11) + (size_t)p * 128 + t] = v; }
                else         zwh[((size_t)p << 11) + (size_t)(ct - 1) * 128 + t] = v;
            }

            const char* bbuf = (it == 0) ? sm : (sm + ((it & 1) ? 32768 : 0));

#pragma unroll 1
            for (int hf = 0; hf < 2; ++hf) {
                float acol[2];
                if (PASS == 2) {
#pragma unroll
                    for (int f = 0; f < 2; ++f)
                        acol[f] = aS[ct * 128 + wc * 64 + (hf * 2 + f) * 16 + lo];
                }
                f32x4 acc[4][2] = {};
                __builtin_amdgcn_s_setprio(1);
#pragma unroll
                for (int s = 0; s < 4; ++s) {
                    const unsigned inr = ((unsigned)(s * 64 + hi * 16)) ^ sx;
                    half8 b[2];
#pragma unroll
                    for (int f = 0; f < 2; ++f)
                        b[f] = *(const half8*)(bbuf + (rowB + (unsigned)(hf * 2 + f) * 16) * 256 + inr);
#pragma unroll
                    for (int fm = 0; fm < 4; ++fm)
#pragma unroll
                        for (int fn = 0; fn < 2; ++fn)
                            acc[fm][fn] = __builtin_amdgcn_mfma_f32_16x16x32_f16(
                                afr[fm][s], b[fn], acc[fm][fn], 0, 0, 0);
                }
                __builtin_amdgcn_s_setprio(0);

                float cs[2] = {0.f, 0.f};
#pragma unroll
                for (int fm = 0; fm < 4; ++fm)
#pragma unroll
                    for (int fn = 0; fn < 2; ++fn)
#pragma unroll
                        for (int r = 0; r < 4; ++r) {
                            const float e = fast_exp2(acc[fm][fn][r]);
                            if (PASS == 1) { rs[fm][r] += e; cs[fn] += e; }
                            else           { cs[fn] += ar[fm][r] * e;
                                             if (it > 0) rs[fm][r] += acol[fn] * e; }
                        }
                if (!(PASS == 1 && it == 0)) {      // pass1 diag: rows only
#pragma unroll
                    for (int fn = 0; fn < 2; ++fn) {
                        cs[fn] += __shfl_xor(cs[fn], 16, 64);
                        cs[fn] += __shfl_xor(cs[fn], 32, 64);
                    }
                    if (lane < 16) {
#pragma unroll
                        for (int fn = 0; fn < 2; ++fn)
                            csum[it & 1][wr][wc * 64 + (hf * 2 + fn) * 16 + lane] = cs[fn];
                    }
                }
            }
        }

        // ---- panel end: rs over 16 col-lanes; flush zfin + last csum column
#pragma unroll
        for (int fm = 0; fm < 4; ++fm)
#pragma unroll
            for (int r = 0; r < 4; ++r) {
                float v = rs[fm][r];
                v += __shfl_xor(v, 1, 64);
                v += __shfl_xor(v, 2, 64);
                v += __shfl_xor(v, 4, 64);
                v += __shfl_xor(v, 8, 64);
                if (lo == 0) zfin[wc][wr * 64 + fm * 16 + hi * 4 + r] = v;
            }
        __syncthreads();
        if (t < 128) {
            zwh[((size_t)15 << 11) + ((size_t)p << 7) + t] = zfin[0][t] + zfin[1][t];
            const int pr = NS & 1;
            const float v = csum[pr][0][t] + csum[pr][1][t];
            if (NS == 0) { if (PASS == 2) zwh[((size_t)16 << 11) + (size_t)p * 128 + t] = v; }
            else         zwh[((size_t)p << 11) + (size_t)(p + NS) * 128 + t] = v;
        }
    }
}

// ---------------------------------------------------------------------------
// Kernel 3: Z[l] = slot15 + sum_{p<q} slot_p ; Ainv = 1/Z   (q = l>>7)
// ---------------------------------------------------------------------------
__global__ __launch_bounds__(256) void k_reduceZ(const float* __restrict__ zp,
                                                 float* __restrict__ ainv) {
    const int i = blockIdx.x * 256 + threadIdx.x;   // over H_*L_
    const int h = i >> 11, l = i & 2047, q = l >> 7;
    const float* zh = zp + (size_t)h * SLOTS * 2048;
    float z = zh[((size_t)15 << 11) + l];
#pragma unroll
    for (int p = 0; p < 15; ++p)
        if (p < q) z += zh[((size_t)p << 11) + l];
    ainv[i] = 1.0f / z;
}

// ---------------------------------------------------------------------------
// Kernel 4: w = slot15 + slot16 + sum_{p<q} slot_p ; out = (1/L) x . w
// ---------------------------------------------------------------------------
__global__ __launch_bounds__(256) void k_out(const float* __restrict__ x,
                                             const float* __restrict__ wp,
                                             float* __restrict__ out) {
    __shared__ float wl[L_];
    const int h = blockIdx.x >> 2, qb = blockIdx.x & 3;
    const int t = threadIdx.x, lane = t & 63, wid = t >> 6;
    const float* wh = wp + (size_t)h * SLOTS * 2048;
    for (int c = t; c < L_; c += 256) {
        const int q = c >> 7;
        float s = wh[((size_t)15 << 11) + c] + wh[((size_t)16 << 11) + c];
#pragma unroll
        for (int p = 0; p < 15; ++p)
            if (p < q) s += wh[((size_t)p << 11) + c];
        wl[c] = s;
    }
    __syncthreads();
#pragma unroll 1
    for (int it = 0; it < 8; ++it) {
        const int d = qb * 32 + wid * 8 + it;
        const float* xr = x + ((size_t)h * D_ + d) * L_;
        float s = 0.0f;
#pragma unroll
        for (int kk = 0; kk < 8; ++kk) {
            const int m = kk * 256 + lane * 4;
            const float4 xv = *(const float4*)(xr + m);
            const float4 wv = *(const float4*)(wl + m);
            s += xv.x * wv.x + xv.y * wv.y + xv.z * wv.z + xv.w * wv.w;
        }
#pragma unroll
        for (int dm = 1; dm < 64; dm <<= 1) s += __shfl_xor(s, dm, 64);
        if (lane == 0) out[(size_t)h * D_ + d] = s * (1.0f / (float)L_);
    }
}

// ---------------------------------------------------------------------------
extern "C" void kernel_launch(void* const* d_in, const int* in_sizes, int n_in,
                              void* d_out, int out_size, void* d_ws, size_t ws_size,
                              hipStream_t stream) {
    const float* x = (const float*)d_in[0];
    float* out = (float*)d_out;
    char* ws = (char*)d_ws;

    // workspace: xt 33,554,432 | zwp 17 slots = 8,912,896 | ainv 524,288
    __half* xt  = (__half*)(ws);
    float* zwp  = (float*)(ws + 33554432);
    float* ainv = (float*)(ws + 33554432 + 8912896);

    k_transpose<<<dim3(H_, L_ / 64), 256, 0, stream>>>(x, xt);
    k_gemm<1><<<512, 256, 0, stream>>>(xt, ainv, zwp);
    k_reduceZ<<<(H_ * L_) / 256, 256, 0, stream>>>(zwp, ainv);
    k_gemm<2><<<512, 256, 0, stream>>>(xt, ainv, zwp);
    k_out<<<H_ * 4, 256, 0, stream>>>(x, zwp, out);
}